// Round 7
// baseline (230.524 us; speedup 1.0000x reference)
//
#include <hip/hip_runtime.h>
#include <math.h>

// Problem constants: N=2, C_out=64, C_in=3, H=256, Wf=129, irfft2 to 256x256
#define H_   256
#define Wf_  129
#define HWf_ 33024      // 256*129
#define CIN_ 3
#define COUT_ 64
#define TW_  0.0245436926f   // 2*pi/256

typedef float f32x4 __attribute__((ext_vector_type(4)));

#define NTL(p) __builtin_nontemporal_load((const f32x4*)(p))

// ---------------------------------------------------------------------------
// Stage 1: Xhat[n,ci,hw] = X[ci] + (1/64) * sum_co D[ci]*(Y/a - num/den)
//   num = Y*sum|D|^2 + a*sum(conj(D)*X),  den = a*sum|D|^2 + a^2,  a=alpha/3
// R4 mapping (best so far): pl=tid&15 -> 16 hw-pairs, cog=tid>>4 -> 16
// co-groups x 4 co. NEW: software-pipelined register double-buffer — issue
// co k+1's 4 loads BEFORE computing co k, so the memory pipe stays busy
// during VALU phases. launch_bounds(256,5) to keep >=5 waves/SIMD.
// ---------------------------------------------------------------------------
__global__ __launch_bounds__(256, 5) void solve_stage1(
    const float* __restrict__ X, const float* __restrict__ D,
    const float* __restrict__ Y, const float* __restrict__ alpha,
    float* __restrict__ Xhat)
{
    const int tid  = threadIdx.x;
    const int pl   = tid & 15;              // pair lane 0..15
    const int cog  = tid >> 4;              // co-group 0..15
    const int pair = blockIdx.x * 16 + pl;
    const int pos0 = pair * 2;              // global complex position
    const int n    = pos0 / HWf_;           // uniform per block
    const int hw0  = pos0 - n * HWf_;

    const float a    = alpha[n] * (1.0f / 3.0f);
    const float inva = 1.0f / a;
    const float a2   = a * a;

    f32x4 x[3];
#pragma unroll
    for (int ci = 0; ci < 3; ++ci)
        x[ci] = *(const f32x4*)(X + ((size_t)(n * 3 + ci) * HWf_ + hw0) * 2);

    const int co0 = cog * 4;
    const float* Dp = D + ((size_t)(n * 64 + co0) * 3) * (HWf_ * 2) + hw0 * 2;
    const float* Yp = Y + ((size_t)(n * 64 + co0)) * (HWf_ * 2) + hw0 * 2;
    const size_t YS = (size_t)(HWf_ * 2);       // co stride in Y (floats)
    const size_t DS = (size_t)(HWf_ * 2);       // (co,ci) row stride in D

    // acc layout: q = pos*6 + ci*2 + (0=re,1=im)
    float acc[12];
#pragma unroll
    for (int q = 0; q < 12; ++q) acc[q] = 0.f;

    // prologue: loads for co=0
    f32x4 yc  = NTL(Yp);
    f32x4 d0c = NTL(Dp + 0 * DS);
    f32x4 d1c = NTL(Dp + 1 * DS);
    f32x4 d2c = NTL(Dp + 2 * DS);

#pragma unroll
    for (int co = 0; co < 4; ++co) {
        f32x4 yn, d0n, d1n, d2n;
        if (co < 3) {   // issue next batch before computing current
            yn  = NTL(Yp + (size_t)(co + 1) * YS);
            d0n = NTL(Dp + (size_t)((co + 1) * 3 + 0) * DS);
            d1n = NTL(Dp + (size_t)((co + 1) * 3 + 1) * DS);
            d2n = NTL(Dp + (size_t)((co + 1) * 3 + 2) * DS);
        }
        const f32x4 y = yc, d0 = d0c, d1 = d1c, d2 = d2c;
        // position 0 (components 0=re,1=im)
        {
            float s2 = d0[0]*d0[0] + d0[1]*d0[1] + d1[0]*d1[0] + d1[1]*d1[1]
                     + d2[0]*d2[0] + d2[1]*d2[1];
            float sr = d0[0]*x[0][0] + d0[1]*x[0][1] + d1[0]*x[1][0] + d1[1]*x[1][1]
                     + d2[0]*x[2][0] + d2[1]*x[2][1];
            float si = d0[0]*x[0][1] - d0[1]*x[0][0] + d1[0]*x[1][1] - d1[1]*x[1][0]
                     + d2[0]*x[2][1] - d2[1]*x[2][0];
            float nr = y[0] * s2 + a * sr, ni = y[1] * s2 + a * si;
            float invden = 1.0f / (a * s2 + a2);
            float tr = y[0] * inva - nr * invden;
            float ti = y[1] * inva - ni * invden;
            acc[0] += d0[0]*tr - d0[1]*ti;  acc[1] += d0[0]*ti + d0[1]*tr;
            acc[2] += d1[0]*tr - d1[1]*ti;  acc[3] += d1[0]*ti + d1[1]*tr;
            acc[4] += d2[0]*tr - d2[1]*ti;  acc[5] += d2[0]*ti + d2[1]*tr;
        }
        // position 1 (components 2=re,3=im)
        {
            float s2 = d0[2]*d0[2] + d0[3]*d0[3] + d1[2]*d1[2] + d1[3]*d1[3]
                     + d2[2]*d2[2] + d2[3]*d2[3];
            float sr = d0[2]*x[0][2] + d0[3]*x[0][3] + d1[2]*x[1][2] + d1[3]*x[1][3]
                     + d2[2]*x[2][2] + d2[3]*x[2][3];
            float si = d0[2]*x[0][3] - d0[3]*x[0][2] + d1[2]*x[1][3] - d1[3]*x[1][2]
                     + d2[2]*x[2][3] - d2[3]*x[2][2];
            float nr = y[2] * s2 + a * sr, ni = y[3] * s2 + a * si;
            float invden = 1.0f / (a * s2 + a2);
            float tr = y[2] * inva - nr * invden;
            float ti = y[3] * inva - ni * invden;
            acc[6]  += d0[2]*tr - d0[3]*ti;  acc[7]  += d0[2]*ti + d0[3]*tr;
            acc[8]  += d1[2]*tr - d1[3]*ti;  acc[9]  += d1[2]*ti + d1[3]*tr;
            acc[10] += d2[2]*tr - d2[3]*ti;  acc[11] += d2[2]*ti + d2[3]*tr;
        }
        if (co < 3) { yc = yn; d0c = d0n; d1c = d1n; d2c = d2n; }
    }

    __shared__ float red[16 * 192];   // [cog][pair][q] = 12 KB
    {
        const int base = cog * 192 + pl * 12;
#pragma unroll
        for (int q = 0; q < 12; ++q) red[base + q] = acc[q];
    }
    __syncthreads();

    if (tid < 192) {
        float s = 0.f;
#pragma unroll
        for (int c = 0; c < 16; ++c) s += red[c * 192 + tid];
        const int P   = tid / 12;
        const int r   = tid - P * 12;
        const int pos = r / 6;
        const int rr  = r - pos * 6;
        const int ci  = rr >> 1;
        const int cc  = rr & 1;
        const int gp  = (blockIdx.x * 16 + P) * 2 + pos;
        const int hw  = gp - n * HWf_;
        const size_t o = ((size_t)(n * 3 + ci) * HWf_ + hw) * 2 + cc;
        Xhat[o] = X[o] + s * (1.0f / 64.0f);
    }
}

// ---------------------------------------------------------------------------
// Stage 2: inverse complex DFT along h (length 256, 1/256 norm).
//   out[h] = (1/256) sum_k in[k] e^{+i 2pi k h/256}
// Block = 128 threads, one column (n_ci,w); thread t computes h=t and h=t+128
// (twiddle differs by (-1)^k). Twiddle via register recurrence, exact refresh
// every 32 steps from integer-reduced argument.
// ---------------------------------------------------------------------------
__global__ __launch_bounds__(128) void solve_stage2(
    const float2* __restrict__ in, float2* __restrict__ out)
{
    __shared__ float2 col[256];

    const int b    = blockIdx.x;        // n_ci*129 + w, 774 blocks
    const int n_ci = b / Wf_;
    const int w    = b - n_ci * Wf_;
    const int t    = threadIdx.x;       // 0..127

    const float2* src = in + (size_t)n_ci * HWf_ + w;
    col[t]       = src[t * Wf_];
    col[t + 128] = src[(t + 128) * Wf_];
    __syncthreads();

    float wc, wsn;
    sincosf((float)t * TW_, &wsn, &wc);   // step multiplier e^{i*2pi*t/256}

    float ar = 0.f, ai = 0.f, br = 0.f, bi = 0.f;
    for (int kb = 0; kb < 8; ++kb) {
        const int k0 = kb * 32;
        float tr, ti;
        {
            const int m = (t * k0) & 255;     // exact integer phase reduction
            float s, c; sincosf((float)m * TW_, &s, &c);
            tr = c; ti = s;
        }
#pragma unroll
        for (int j = 0; j < 32; ++j) {
            const float2 v = col[k0 + j];     // broadcast, conflict-free
            const float pr = v.x * tr - v.y * ti;
            const float pi = v.x * ti + v.y * tr;
            ar += pr; ai += pi;
            if ((k0 + j) & 1) { br -= pr; bi -= pi; }
            else             { br += pr; bi += pi; }
            const float nt = tr * wc - ti * wsn;
            ti = tr * wsn + ti * wc;
            tr = nt;
        }
    }

    float2* dst = out + (size_t)n_ci * HWf_ + w;
    dst[t * Wf_]         = make_float2(ar * (1.0f / 256.0f), ai * (1.0f / 256.0f));
    dst[(t + 128) * Wf_] = make_float2(br * (1.0f / 256.0f), bi * (1.0f / 256.0f));
}

// ---------------------------------------------------------------------------
// Stage 3: c2r inverse DFT along w (n=256 from 129 bins, 1/256 norm),
// numpy semantics (imag of bins 0 and 128 ignored):
//   x[m] = (1/256)[X0.re + (-1)^m X128.re + 2 sum_{k=1}^{127}(Xr cos - Xi sin)]
// Block = 128 threads, one row; thread t computes m=t and m=t+128.
// ---------------------------------------------------------------------------
__global__ __launch_bounds__(128) void solve_stage3(
    const float2* __restrict__ in, float* __restrict__ out)
{
    __shared__ float2 row[Wf_];

    const int b = blockIdx.x;           // (n*3+ci)*256 + h, 1536 blocks
    const int t = threadIdx.x;          // 0..127

    row[t] = in[(size_t)b * Wf_ + t];
    if (t == 0) row[128] = in[(size_t)b * Wf_ + 128];
    __syncthreads();

    float wc, wsn;
    sincosf((float)t * TW_, &wsn, &wc);

    float sa = 0.f, sb = 0.f;           // sums over k=0..127 for m=t, m=t+128
    for (int kb = 0; kb < 4; ++kb) {
        const int k0 = kb * 32;
        float tr, ti;
        {
            const int m = (t * k0) & 255;
            float s, c; sincosf((float)m * TW_, &s, &c);
            tr = c; ti = s;
        }
#pragma unroll
        for (int j = 0; j < 32; ++j) {
            const float2 v = row[k0 + j];     // broadcast
            const float pr = v.x * tr - v.y * ti;   // Re(X_k e^{+i th})
            sa += pr;
            if ((k0 + j) & 1) sb -= pr; else sb += pr;
            const float nt = tr * wc - ti * wsn;
            ti = tr * wsn + ti * wc;
            tr = nt;
        }
    }

    const float sgn  = (t & 1) ? -1.0f : 1.0f;     // (-1)^m, same for m and m+128
    const float base = -0.5f * row[0].x + sgn * 0.5f * row[128].x;
    out[(size_t)b * 256 + t]       = (sa + base) * (1.0f / 128.0f);
    out[(size_t)b * 256 + t + 128] = (sb + base) * (1.0f / 128.0f);
}

// ---------------------------------------------------------------------------
extern "C" void kernel_launch(void* const* d_in, const int* in_sizes, int n_in,
                              void* d_out, int out_size, void* d_ws, size_t ws_size,
                              hipStream_t stream) {
    const float* X     = (const float*)d_in[0];  // (2,1,3,256,129,2)
    const float* D     = (const float*)d_in[1];  // (2,64,3,256,129,2)
    const float* Y     = (const float*)d_in[2];  // (2,64,1,256,129,2)
    const float* alpha = (const float*)d_in[3];  // (2,)
    // d_in[4] = x_size (int64[2]) -- hardcoded 256x256

    float* ws1 = (float*)d_ws;                       // Xhat: 6*33024 cplx
    float2* ws2 = (float2*)(ws1 + (size_t)CIN_ * 2 * HWf_ * 2);

    solve_stage1<<<2064, 256, 0, stream>>>(X, D, Y, alpha, ws1);
    solve_stage2<<<2 * CIN_ * Wf_, 128, 0, stream>>>((const float2*)ws1, ws2);
    solve_stage3<<<2 * CIN_ * H_, 128, 0, stream>>>(ws2, (float*)d_out);
}

// Round 8
// 209.814 us; speedup vs baseline: 1.0987x; 1.0987x over previous
//
#include <hip/hip_runtime.h>
#include <math.h>

// Problem constants: N=2, C_out=64, C_in=3, H=256, Wf=129, irfft2 to 256x256
#define H_   256
#define Wf_  129
#define HWf_ 33024        // 256*129 complex per (n,ci) plane
#define NPAIRS_ 16512     // complex-pairs per n (= HWf_/2)
#define CIN_ 3
#define COUT_ 64
#define TW_  0.0245436926f   // 2*pi/256
#define PARTF_ 396288     // floats per partial buffer = 2*3*33024*2
#define PART4_ 99072      // f32x4 per partial buffer

typedef float f32x4 __attribute__((ext_vector_type(4)));
#define NTL(p) __builtin_nontemporal_load((const f32x4*)(p))

// ---------------------------------------------------------------------------
// Stage 1 (streaming): parts[q][n,ci,hw] = sum_{co in quad q} D[ci]*t(co,hw),
//   t = Y/a - num/den; num = Y*s2 + a*(conj(D)·X); den = a*s2 + a^2; a=alpha/3
// Block = (n, co-quad q, hw-chunk c); 4 waves ALL on quad q; lane+wave tile
// 256 consecutive hw-pairs per step, 2 steps/block -> every (co,ci) stream is
// a sequential 8KB run (DRAM page locality — the R4 pattern had none).
// No LDS, no barriers: each thread writes its quad-sum directly (3 coalesced
// 16B stores). Grid 1056 = 2n x 16q x 33c; 16 waves/CU.
// ---------------------------------------------------------------------------
__global__ __launch_bounds__(256) void solve_stage1(
    const float* __restrict__ X, const float* __restrict__ D,
    const float* __restrict__ Y, const float* __restrict__ alpha,
    float* __restrict__ parts)
{
    const int tid = threadIdx.x;
    const int q   = blockIdx.x & 15;        // co-quad 0..15
    const int t2  = blockIdx.x >> 4;        // n*33 + c
    const int n   = (t2 >= 33) ? 1 : 0;
    const int c   = t2 - n * 33;

    const float a    = alpha[n] * (1.0f / 3.0f);
    const float inva = 1.0f / a;
    const float a2   = a * a;

    const int co0 = q * 4;
    const float* Dbase = D + ((size_t)(n * 64 + co0) * 3) * (HWf_ * 2);
    const float* Ybase = Y + ((size_t)(n * 64 + co0)) * (HWf_ * 2);
    const float* Xbase = X + (size_t)n * 3 * (HWf_ * 2);
    float*       Pq    = parts + (size_t)q * PARTF_ + (size_t)n * 3 * (HWf_ * 2);

#pragma unroll
    for (int s = 0; s < 2; ++s) {
        const int pair = c * 512 + s * 256 + tid;   // tid = w*64+l: 256 consec
        if (pair < NPAIRS_) {
            const int hw0 = pair * 2;
            const size_t off = (size_t)hw0 * 2;     // float offset within plane

            f32x4 x0 = *(const f32x4*)(Xbase + 0 * (HWf_ * 2) + off);
            f32x4 x1 = *(const f32x4*)(Xbase + 1 * (HWf_ * 2) + off);
            f32x4 x2 = *(const f32x4*)(Xbase + 2 * (HWf_ * 2) + off);

            f32x4 yv[4], dv[12];
#pragma unroll
            for (int j = 0; j < 4; ++j) {
                yv[j]       = NTL(Ybase + (size_t)j * (HWf_ * 2) + off);
                dv[j*3 + 0] = NTL(Dbase + ((size_t)j * 3 + 0) * (HWf_ * 2) + off);
                dv[j*3 + 1] = NTL(Dbase + ((size_t)j * 3 + 1) * (HWf_ * 2) + off);
                dv[j*3 + 2] = NTL(Dbase + ((size_t)j * 3 + 2) * (HWf_ * 2) + off);
            }

            float acc[12];
#pragma unroll
            for (int k = 0; k < 12; ++k) acc[k] = 0.f;

#pragma unroll
            for (int j = 0; j < 4; ++j) {
                const f32x4 y  = yv[j];
                const f32x4 d0 = dv[j*3 + 0];
                const f32x4 d1 = dv[j*3 + 1];
                const f32x4 d2 = dv[j*3 + 2];
                // position 0 (components 0=re,1=im)
                {
                    float s2 = d0[0]*d0[0] + d0[1]*d0[1] + d1[0]*d1[0] + d1[1]*d1[1]
                             + d2[0]*d2[0] + d2[1]*d2[1];
                    float sr = d0[0]*x0[0] + d0[1]*x0[1] + d1[0]*x1[0] + d1[1]*x1[1]
                             + d2[0]*x2[0] + d2[1]*x2[1];
                    float si = d0[0]*x0[1] - d0[1]*x0[0] + d1[0]*x1[1] - d1[1]*x1[0]
                             + d2[0]*x2[1] - d2[1]*x2[0];
                    float nr = y[0] * s2 + a * sr, ni = y[1] * s2 + a * si;
                    float invden = 1.0f / (a * s2 + a2);
                    float tr = y[0] * inva - nr * invden;
                    float ti = y[1] * inva - ni * invden;
                    acc[0] += d0[0]*tr - d0[1]*ti;  acc[1] += d0[0]*ti + d0[1]*tr;
                    acc[4] += d1[0]*tr - d1[1]*ti;  acc[5] += d1[0]*ti + d1[1]*tr;
                    acc[8] += d2[0]*tr - d2[1]*ti;  acc[9] += d2[0]*ti + d2[1]*tr;
                }
                // position 1 (components 2=re,3=im)
                {
                    float s2 = d0[2]*d0[2] + d0[3]*d0[3] + d1[2]*d1[2] + d1[3]*d1[3]
                             + d2[2]*d2[2] + d2[3]*d2[3];
                    float sr = d0[2]*x0[2] + d0[3]*x0[3] + d1[2]*x1[2] + d1[3]*x1[3]
                             + d2[2]*x2[2] + d2[3]*x2[3];
                    float si = d0[2]*x0[3] - d0[3]*x0[2] + d1[2]*x1[3] - d1[3]*x1[2]
                             + d2[2]*x2[3] - d2[3]*x2[2];
                    float nr = y[2] * s2 + a * sr, ni = y[3] * s2 + a * si;
                    float invden = 1.0f / (a * s2 + a2);
                    float tr = y[2] * inva - nr * invden;
                    float ti = y[3] * inva - ni * invden;
                    acc[2]  += d0[2]*tr - d0[3]*ti;  acc[3]  += d0[2]*ti + d0[3]*tr;
                    acc[6]  += d1[2]*tr - d1[3]*ti;  acc[7]  += d1[2]*ti + d1[3]*tr;
                    acc[10] += d2[2]*tr - d2[3]*ti;  acc[11] += d2[2]*ti + d2[3]*tr;
                }
            }

            // acc layout now: [ci*4 + (pos0re,pos0im,pos1re,pos1im)] -> one
            // f32x4 store per ci at (hw0, hw0+1) interleaved complex. Coalesced
            // across lanes (stride 16B).
#pragma unroll
            for (int ci = 0; ci < 3; ++ci) {
                f32x4 v; v[0] = acc[ci*4+0]; v[1] = acc[ci*4+1];
                         v[2] = acc[ci*4+2]; v[3] = acc[ci*4+3];
                *(f32x4*)(Pq + (size_t)ci * (HWf_ * 2) + off) = v;
            }
        }
    }
}

// ---------------------------------------------------------------------------
// Combine: Xhat = X + (sum of 16 quad-partials)/64. Fully coalesced f32x4.
// 99072 f32x4 elements; partials are L3-hot (just written).
// ---------------------------------------------------------------------------
__global__ __launch_bounds__(256) void solve_combine(
    const f32x4* __restrict__ X4, const f32x4* __restrict__ P4,
    f32x4* __restrict__ out4)
{
    const int i = blockIdx.x * 256 + threadIdx.x;   // 387*256 = 99072 exact
    f32x4 s = P4[i];
#pragma unroll
    for (int k = 1; k < 16; ++k) s += P4[i + (size_t)k * PART4_];
    out4[i] = X4[i] + s * (1.0f / 64.0f);
}

// ---------------------------------------------------------------------------
// Stage 2: inverse complex DFT along h (length 256, 1/256 norm).
//   out[h] = (1/256) sum_k in[k] e^{+i 2pi k h/256}
// Block = 128 threads, one column (n_ci,w); thread t computes h=t and h=t+128.
// ---------------------------------------------------------------------------
__global__ __launch_bounds__(128) void solve_stage2(
    const float2* __restrict__ in, float2* __restrict__ out)
{
    __shared__ float2 col[256];

    const int b    = blockIdx.x;        // n_ci*129 + w, 774 blocks
    const int n_ci = b / Wf_;
    const int w    = b - n_ci * Wf_;
    const int t    = threadIdx.x;       // 0..127

    const float2* src = in + (size_t)n_ci * HWf_ + w;
    col[t]       = src[t * Wf_];
    col[t + 128] = src[(t + 128) * Wf_];
    __syncthreads();

    float wc, wsn;
    sincosf((float)t * TW_, &wsn, &wc);   // step multiplier e^{i*2pi*t/256}

    float ar = 0.f, ai = 0.f, br = 0.f, bi = 0.f;
    for (int kb = 0; kb < 8; ++kb) {
        const int k0 = kb * 32;
        float tr, ti;
        {
            const int m = (t * k0) & 255;     // exact integer phase reduction
            float s, c2; sincosf((float)m * TW_, &s, &c2);
            tr = c2; ti = s;
        }
#pragma unroll
        for (int j = 0; j < 32; ++j) {
            const float2 v = col[k0 + j];     // broadcast, conflict-free
            const float pr = v.x * tr - v.y * ti;
            const float pi = v.x * ti + v.y * tr;
            ar += pr; ai += pi;
            if ((k0 + j) & 1) { br -= pr; bi -= pi; }
            else             { br += pr; bi += pi; }
            const float nt = tr * wc - ti * wsn;
            ti = tr * wsn + ti * wc;
            tr = nt;
        }
    }

    float2* dst = out + (size_t)n_ci * HWf_ + w;
    dst[t * Wf_]         = make_float2(ar * (1.0f / 256.0f), ai * (1.0f / 256.0f));
    dst[(t + 128) * Wf_] = make_float2(br * (1.0f / 256.0f), bi * (1.0f / 256.0f));
}

// ---------------------------------------------------------------------------
// Stage 3: c2r inverse DFT along w (n=256 from 129 bins, 1/256 norm),
// numpy semantics (imag of bins 0 and 128 ignored):
//   x[m] = (1/256)[X0.re + (-1)^m X128.re + 2 sum_{k=1}^{127}(Xr cos - Xi sin)]
// Block = 128 threads, one row; thread t computes m=t and m=t+128.
// ---------------------------------------------------------------------------
__global__ __launch_bounds__(128) void solve_stage3(
    const float2* __restrict__ in, float* __restrict__ out)
{
    __shared__ float2 row[Wf_];

    const int b = blockIdx.x;           // (n*3+ci)*256 + h, 1536 blocks
    const int t = threadIdx.x;          // 0..127

    row[t] = in[(size_t)b * Wf_ + t];
    if (t == 0) row[128] = in[(size_t)b * Wf_ + 128];
    __syncthreads();

    float wc, wsn;
    sincosf((float)t * TW_, &wsn, &wc);

    float sa = 0.f, sb = 0.f;           // sums over k=0..127 for m=t, m=t+128
    for (int kb = 0; kb < 4; ++kb) {
        const int k0 = kb * 32;
        float tr, ti;
        {
            const int m = (t * k0) & 255;
            float s, c2; sincosf((float)m * TW_, &s, &c2);
            tr = c2; ti = s;
        }
#pragma unroll
        for (int j = 0; j < 32; ++j) {
            const float2 v = row[k0 + j];     // broadcast
            const float pr = v.x * tr - v.y * ti;   // Re(X_k e^{+i th})
            sa += pr;
            if ((k0 + j) & 1) sb -= pr; else sb += pr;
            const float nt = tr * wc - ti * wsn;
            ti = tr * wsn + ti * wc;
            tr = nt;
        }
    }

    const float sgn  = (t & 1) ? -1.0f : 1.0f;     // (-1)^m, same for m and m+128
    const float base = -0.5f * row[0].x + sgn * 0.5f * row[128].x;
    out[(size_t)b * 256 + t]       = (sa + base) * (1.0f / 128.0f);
    out[(size_t)b * 256 + t + 128] = (sb + base) * (1.0f / 128.0f);
}

// ---------------------------------------------------------------------------
extern "C" void kernel_launch(void* const* d_in, const int* in_sizes, int n_in,
                              void* d_out, int out_size, void* d_ws, size_t ws_size,
                              hipStream_t stream) {
    const float* X     = (const float*)d_in[0];  // (2,1,3,256,129,2)
    const float* D     = (const float*)d_in[1];  // (2,64,3,256,129,2)
    const float* Y     = (const float*)d_in[2];  // (2,64,1,256,129,2)
    const float* alpha = (const float*)d_in[3];  // (2,)
    // d_in[4] = x_size (int64[2]) -- hardcoded 256x256

    float*  parts = (float*)d_ws;                        // 16 x 1.585 MB
    float*  xhat  = parts + (size_t)16 * PARTF_;         // combined Xhat
    float2* ws2   = (float2*)(xhat + PARTF_);            // h-ifft out

    solve_stage1<<<1056, 256, 0, stream>>>(X, D, Y, alpha, parts);
    solve_combine<<<387, 256, 0, stream>>>(
        (const f32x4*)X, (const f32x4*)parts, (f32x4*)xhat);
    solve_stage2<<<2 * CIN_ * Wf_, 128, 0, stream>>>((const float2*)xhat, ws2);
    solve_stage3<<<2 * CIN_ * H_, 128, 0, stream>>>(ws2, (float*)d_out);
}